// Round 9
// baseline (137.104 us; speedup 1.0000x reference)
//
#include <hip/hip_runtime.h>

// SpikingReadoutLayer, fused via decoupled lookback:
//   h2[b,t,o] = sum_h in[b,t,h] * W[h,o]
//   flt' = a*flt + h_t ; out' = b*out + flt (OLD flt); out_rec[b,0,:]=0
//
// One block per (b, chunk of 250 rows) — R5's verified stage/compute/scan
// skeleton (36 KB LDS, 4 blocks/CU, whole grid co-resident). After the
// block-local scan each block publishes its 16 (flt,out) chunk-final states
// as 64-bit agent-scope release stores into ws, then acquire-spins on its
// <=7 predecessors (all LOWER blockIdx -> dispatched earlier; no deadlock),
// combines them with the closed form of A^k (A=[[a,0],[1,b]] =>
// A^k=[[a^k,0],[g_k,b^k]], g_k=(a^k-b^k)/(a-b)), and writes the CORRECTED
// output straight from LDS — no second kernel, no 32 MB RMW pass.
// Signal = payload itself: ws pre-memset to 0xFF (NaN:NaN, unreachable from
// finite arithmetic) each call -> deterministic across graph replays.

constexpr int B_ = 128, T_ = 2000, H_ = 256, O_ = 16;
constexpr int TOUT = T_ + 1;                 // 2001
constexpr int CHUNKS = 8, CL = 250;          // 8*250 = 2000
constexpr int HC = 32;                       // h per stage chunk (8 chunks)
constexpr int SSTR = 36;                     // stage row stride (floats)
constexpr int PAD = 20;                      // scan tile row stride (floats)
constexpr float ALPHA = 0.95f, BETA = 0.9f;
constexpr float INV_AB = 20.0f;              // 1/(ALPHA-BETA)
constexpr float L2A = -0.07400058144377693f; // log2(0.95)
constexpr float L2B = -0.15200309344504997f; // log2(0.90)
constexpr unsigned long long SENTINEL = 0xFFFFFFFFFFFFFFFFull;

__global__ __launch_bounds__(256, 4)
void fused_kernel(const float* __restrict__ in, const float* __restrict__ W,
                  float* __restrict__ out, unsigned long long* __restrict__ ws) {
    __shared__ float buf[CL * SSTR];   // 36 KB; stage buffer, reused as scan tile
    __shared__ float f0s[O_], o0s[O_];
    const int tid = threadIdx.x;
    const int b = blockIdx.x >> 3;     // CHUNKS = 8
    const int j = blockIdx.x & 7;

    const float* inb = in + ((size_t)b * T_ + (size_t)j * CL) * H_;
    const int row = (tid < CL) ? tid : 0;   // clamp: uniform control flow

    float acc[16];
#pragma unroll
    for (int o = 0; o < 16; ++o) acc[o] = 0.f;

    for (int c = 0; c < CHUNKS; ++c) {
        // ---- stage chunk [CL rows x 32 h] into LDS, coalesced ----
#pragma unroll
        for (int it = 0; it < 8; ++it) {
            const int f = it * 256 + tid;
            if (f < CL * 8) {
                const int r = f >> 3, q = f & 7;
                const float4 v =
                    *(const float4*)(inb + (size_t)r * H_ + c * HC + 4 * q);
                *(float4*)&buf[r * SSTR + 4 * q] = v;
            }
        }
        __syncthreads();

        // ---- compute: thread-per-row, 32 h x 16 o FMAs from LDS ----
        const float* __restrict__ Wc = W + c * HC * O_;  // wave-uniform reads
#pragma unroll
        for (int q = 0; q < 8; ++q) {
            const float4 v = *(const float4*)&buf[row * SSTR + 4 * q];
            const float xv[4] = {v.x, v.y, v.z, v.w};
#pragma unroll
            for (int e = 0; e < 4; ++e) {
                const float x = xv[e];
                const float* wrow = Wc + (4 * q + e) * 16;
#pragma unroll
                for (int o = 0; o < 16; ++o)
                    acc[o] = fmaf(x, wrow[o], acc[o]);
            }
        }
        __syncthreads();
    }

    // ---- acc -> scan tile (reuses buf; all stage reads done) ----
    if (tid < CL) {
        float4* tp = (float4*)&buf[tid * PAD];
        tp[0] = make_float4(acc[0],  acc[1],  acc[2],  acc[3]);
        tp[1] = make_float4(acc[4],  acc[5],  acc[6],  acc[7]);
        tp[2] = make_float4(acc[8],  acc[9],  acc[10], acc[11]);
        tp[3] = make_float4(acc[12], acc[13], acc[14], acc[15]);
    }
    __syncthreads();

    // ---- 16 serial chains down the columns; publish; lookback ----
    if (tid < O_) {
        float flt = 0.f, oo = 0.f;
        float* col = &buf[tid];
#pragma unroll 5
        for (int t = 0; t < CL; ++t) {
            const float h = col[t * PAD];
            const float no = fmaf(BETA, oo, flt);  // uses OLD flt
            flt = fmaf(ALPHA, flt, h);
            col[t * PAD] = no;
            oo = no;
        }
        // publish local chunk-final state (payload is the signal)
        const unsigned long long pay =
            ((unsigned long long)__float_as_uint(oo) << 32) | __float_as_uint(flt);
        __hip_atomic_store(&ws[(size_t)(b * CHUNKS + j) * O_ + tid], pay,
                           __ATOMIC_RELEASE, __HIP_MEMORY_SCOPE_AGENT);
        if (j == 0) out[(size_t)b * TOUT * O_ + tid] = 0.f;  // out_rec[b,0,o]

        // lookback: true start state from predecessors (closed form)
        float f = 0.f, oacc = 0.f;
        for (int m = 0; m < j; ++m) {      // all predecessors have LOWER blockIdx
            unsigned long long v;
            do {
                v = __hip_atomic_load(&ws[(size_t)(b * CHUNKS + m) * O_ + tid],
                                      __ATOMIC_ACQUIRE, __HIP_MEMORY_SCOPE_AGENT);
            } while (v == SENTINEL);
            const float sf = __uint_as_float((unsigned)(v & 0xFFFFFFFFu));
            const float so = __uint_as_float((unsigned)(v >> 32));
            const float k  = (float)((j - 1 - m) * CL);
            const float a  = exp2f(k * L2A);
            const float bb = exp2f(k * L2B);
            const float g  = (a - bb) * INV_AB;
            f    = fmaf(a, sf, f);
            oacc = fmaf(g, sf, fmaf(bb, so, oacc));
        }
        f0s[tid] = f;
        o0s[tid] = oacc;
    }
    __syncthreads();

    // ---- corrected float4 writeback straight from LDS (no RMW pass) ----
    float4* ob = (float4*)(out + ((size_t)b * TOUT + (size_t)j * CL + 1) * O_);
#pragma unroll
    for (int it = 0; it < 4; ++it) {              // CL*O_/4 = 1000 float4
        const int e4 = it * 256 + tid;
        if (e4 < CL * 4) {
            const int tloc = e4 >> 2, qo = 4 * (e4 & 3);
            const float k  = (float)(tloc + 1);
            const float a  = exp2f(k * L2A);
            const float bb = exp2f(k * L2B);
            const float g  = (a - bb) * INV_AB;
            const float* tp = &buf[tloc * PAD + qo];
            float4 v;
            v.x = fmaf(g, f0s[qo + 0], fmaf(bb, o0s[qo + 0], tp[0]));
            v.y = fmaf(g, f0s[qo + 1], fmaf(bb, o0s[qo + 1], tp[1]));
            v.z = fmaf(g, f0s[qo + 2], fmaf(bb, o0s[qo + 2], tp[2]));
            v.w = fmaf(g, f0s[qo + 3], fmaf(bb, o0s[qo + 3], tp[3]));
            ob[e4] = v;
        }
    }
}

extern "C" void kernel_launch(void* const* d_in, const int* in_sizes, int n_in,
                              void* d_out, int out_size, void* d_ws, size_t ws_size,
                              hipStream_t stream) {
    const float* in = (const float*)d_in[0];   // [B, T, H]
    const float* W  = (const float*)d_in[1];   // [H, O]
    float* out = (float*)d_out;                // [B, T+1, O]
    unsigned long long* ws = (unsigned long long*)d_ws;  // 128*8*16*8 = 128 KiB

    // reset payload slots to SENTINEL (NaN:NaN) every call -> deterministic
    hipMemsetAsync(d_ws, 0xFF, (size_t)B_ * CHUNKS * O_ * 8, stream);
    fused_kernel<<<dim3(B_ * CHUNKS), dim3(256), 0, stream>>>(in, W, out, ws);
}

// Round 10
// 73.048 us; speedup vs baseline: 1.8769x; 1.8769x over previous
//
#include <hip/hip_runtime.h>

// SpikingReadoutLayer (two-kernel; R5 skeleton + R8's gload_lds pipeline at
// 4-blocks/CU occupancy):
//   h2[b,t,o] = sum_h in[b,t,h] * W[h,o]
//   flt' = a*flt + h_t ; out' = b*out + flt (OLD flt); out_rec[b,0,:]=0
//
// Kernel 1: one block per (b, t-chunk of 250 rows). 16 h-chunks of 16.
// Stage via __builtin_amdgcn_global_load_lds (16B DMA, no VGPR round-trip)
// into double-buffered LINEAR LDS (2 x 16 KB = 32 KB -> 4 blocks/CU kept).
// Issue chunk c+1 -> compute chunk c -> __syncthreads (drains vmcnt) -> swap:
// HBM latency hides under the 256-FMA compute phase. Bank conflicts cut by
// XOR-swizzling the GLOBAL source quad (q^(r&3)) and reading with the same
// XOR (both-sides rule). Thread-per-row compute; W read wave-uniform.
// Block-local scan in LDS (PAD=20, conflict-free), chunk-final states -> ws.
// Kernel 2: closed-form affine fixup (A^k analytic), float4 RMW (verified).

constexpr int B_ = 128, T_ = 2000, H_ = 256, O_ = 16;
constexpr int TOUT = T_ + 1;                 // 2001
constexpr int TC = 8, CL = 250;              // t-chunks per batch
constexpr int NHC = 16, HC = 16;             // h-chunks of 16
constexpr int BUFSLOTS = 1024;               // 16B slots per buffer (>= CL*4)
constexpr int PAD = 20;                      // scan tile row stride (floats)
constexpr float ALPHA = 0.95f, BETA = 0.9f;
constexpr float INV_AB = 20.0f;              // 1/(ALPHA-BETA)
constexpr float L2A = -0.07400058144377693f; // log2(0.95)
constexpr float L2B = -0.15200309344504997f; // log2(0.90)

#define AS1 __attribute__((address_space(1)))
#define AS3 __attribute__((address_space(3)))

__device__ __forceinline__ void gload16(const float* g, float* l) {
    __builtin_amdgcn_global_load_lds((const AS1 void*)g, (AS3 void*)l, 16, 0, 0);
}

// Stage one [CL x 16] h-chunk: slot f=(r,q) <- global quad (q ^ (r&3)) of
// row r. LDS dest linear (wave-uniform base + lane*16); the swizzle lives in
// the global source, whose per-row 64B address set is unchanged -> coalesced.
// Tail slots (f >= 1000) clamp r to CL-1: written, never read.
__device__ __forceinline__ void stage_chunk(const float* __restrict__ inb, int c,
                                            float* dst, int tid) {
#pragma unroll
    for (int it = 0; it < 4; ++it) {
        const int f = it * 256 + tid;
        int r = f >> 2;
        if (r > CL - 1) r = CL - 1;
        const int q = f & 3;
        const float* g = inb + (size_t)r * H_ + c * HC + 4 * (q ^ (r & 3));
        gload16(g, dst + (size_t)f * 4);
    }
}

__global__ __launch_bounds__(256, 4)
void h2scan_kernel(const float* __restrict__ in, const float* __restrict__ W,
                   float* __restrict__ out, float* __restrict__ ws) {
    __shared__ float lds[2 * BUFSLOTS * 4];   // 32 KB: two linear stage buffers
    const int tid = threadIdx.x;
    const int b = blockIdx.x >> 3;            // TC = 8
    const int j = blockIdx.x & 7;

    const float* inb = in + ((size_t)b * T_ + (size_t)j * CL) * H_;
    const int row = (tid < CL) ? tid : 0;     // clamp for idle tail threads
    const int rsw = row & 3;

    float acc[16];
#pragma unroll
    for (int o = 0; o < 16; ++o) acc[o] = 0.f;

    stage_chunk(inb, 0, &lds[0], tid);
    __syncthreads();                          // drain chunk-0 DMA

    for (int c = 0; c < NHC; ++c) {
        float* cur = &lds[(c & 1) * (BUFSLOTS * 4)];
        if (c + 1 < NHC)                      // issue next chunk; flies during compute
            stage_chunk(inb, c + 1, &lds[((c + 1) & 1) * (BUFSLOTS * 4)], tid);

        // ---- compute: thread-per-row, 16 h x 16 o FMAs from swizzled LDS ----
        const float* __restrict__ Wc = W + c * HC * O_;  // wave-uniform reads
#pragma unroll
        for (int p = 0; p < 4; ++p) {
            const float4 v = *(const float4*)&cur[row * 16 + 4 * (p ^ rsw)];
            const float xv[4] = {v.x, v.y, v.z, v.w};
#pragma unroll
            for (int e = 0; e < 4; ++e) {
                const float x = xv[e];
                const float* wrow = Wc + (4 * p + e) * 16;
#pragma unroll
                for (int o = 0; o < 16; ++o)
                    acc[o] = fmaf(x, wrow[o], acc[o]);
            }
        }
        __syncthreads();   // drains next-chunk DMA; guards buffer reuse
    }

    // ---- acc -> scan tile (overlays buffers; post-barrier, safe) ----
    if (tid < CL) {
        float4* tp = (float4*)&lds[tid * PAD];
        tp[0] = make_float4(acc[0],  acc[1],  acc[2],  acc[3]);
        tp[1] = make_float4(acc[4],  acc[5],  acc[6],  acc[7]);
        tp[2] = make_float4(acc[8],  acc[9],  acc[10], acc[11]);
        tp[3] = make_float4(acc[12], acc[13], acc[14], acc[15]);
    }
    __syncthreads();

    // ---- 16 serial chains down the columns (conflict-free, PAD=20) ----
    if (tid < O_) {
        float flt = 0.f, oo = 0.f;
        float* col = &lds[tid];
#pragma unroll 5
        for (int t = 0; t < CL; ++t) {
            const float h = col[t * PAD];
            const float no = fmaf(BETA, oo, flt);  // uses OLD flt
            flt = fmaf(ALPHA, flt, h);
            col[t * PAD] = no;
            oo = no;
        }
        float* wp = ws + ((size_t)(b * O_ + tid) * TC + j) * 2;
        wp[0] = flt;
        wp[1] = oo;
        if (j == 0) out[(size_t)b * TOUT * O_ + tid] = 0.f;  // out_rec[b,0,o]
    }
    __syncthreads();

    // ---- coalesced float4 writeback of LOCAL outputs ----
    float4* ob = (float4*)(out + ((size_t)b * TOUT + (size_t)j * CL + 1) * O_);
#pragma unroll
    for (int it = 0; it < 4; ++it) {              // CL*O_/4 = 1000 float4
        const int e4 = it * 256 + tid;
        if (e4 < CL * 4) {
            const int tloc = e4 >> 2, qo = 4 * (e4 & 3);
            const float* tp = &lds[tloc * PAD + qo];
            ob[e4] = make_float4(tp[0], tp[1], tp[2], tp[3]);
        }
    }
}

// Kernel 2: chunk j>0 start state s0 = sum_{m<j} A^{CL*(j-1-m)} * sigma_m,
// A^k = [[a^k,0],[g_k,b^k]], g_k=(a^k-b^k)/(a-b); then
// out[b, j*CL+tloc+1, o] += g_{tloc+1}*f0[o] + b^{tloc+1}*o0[o]  (float4 RMW).
__global__ __launch_bounds__(256)
void fixup_kernel(float* __restrict__ out, const float* __restrict__ ws) {
    const int blk = blockIdx.x;
    const int b = blk >> 3;
    const int j = blk & 7;
    if (j == 0) return;

    __shared__ float f0s[O_], o0s[O_];
    const int tid = threadIdx.x;
    if (tid < O_) {
        const float* wp = ws + ((size_t)(b * O_ + tid) * TC) * 2;
        float f = 0.f, oacc = 0.f;
        for (int m = 0; m < j; ++m) {      // <= 7 terms
            const float k  = (float)((j - 1 - m) * CL);
            const float a  = exp2f(k * L2A);
            const float bb = exp2f(k * L2B);
            const float g  = (a - bb) * INV_AB;
            const float sf = wp[m * 2 + 0];
            const float so = wp[m * 2 + 1];
            f    = fmaf(a, sf, f);
            oacc = fmaf(g, sf, fmaf(bb, so, oacc));
        }
        f0s[tid] = f;
        o0s[tid] = oacc;
    }
    __syncthreads();

    float4* ob = (float4*)(out + ((size_t)b * TOUT + (size_t)j * CL + 1) * O_);
#pragma unroll
    for (int it = 0; it < 4; ++it) {              // 1000 float4
        const int e4 = it * 256 + tid;
        if (e4 < CL * 4) {
            const int tloc = e4 >> 2, qo = 4 * (e4 & 3);
            const float k  = (float)(tloc + 1);
            const float a  = exp2f(k * L2A);
            const float bb = exp2f(k * L2B);
            const float g  = (a - bb) * INV_AB;
            float4 v = ob[e4];
            v.x = fmaf(g, f0s[qo + 0], fmaf(bb, o0s[qo + 0], v.x));
            v.y = fmaf(g, f0s[qo + 1], fmaf(bb, o0s[qo + 1], v.y));
            v.z = fmaf(g, f0s[qo + 2], fmaf(bb, o0s[qo + 2], v.z));
            v.w = fmaf(g, f0s[qo + 3], fmaf(bb, o0s[qo + 3], v.w));
            ob[e4] = v;
        }
    }
}

extern "C" void kernel_launch(void* const* d_in, const int* in_sizes, int n_in,
                              void* d_out, int out_size, void* d_ws, size_t ws_size,
                              hipStream_t stream) {
    const float* in = (const float*)d_in[0];   // [B, T, H]
    const float* W  = (const float*)d_in[1];   // [H, O]
    float* out = (float*)d_out;                // [B, T+1, O]
    float* ws  = (float*)d_ws;                 // 128*16*8*2*4 B = 128 KiB

    h2scan_kernel<<<dim3(B_ * TC), dim3(256), 0, stream>>>(in, W, out, ws);
    fixup_kernel<<<dim3(B_ * TC), dim3(256), 0, stream>>>(out, ws);
}